// Round 9
// baseline (214.988 us; speedup 1.0000x reference)
//
#include <hip/hip_runtime.h>

// CRF NLL, round 18: 4-way segment split of the serial chain.
//   Z = u^T M^T T_B T_A E_{h1}
//   wv0: gold score, then fwd vector chain E_{h1} (h1 steps)
//   wv2: T_A = prod_{s=h1+1..h2} (diag(fe_s) M^T)    (matrix chain, mA steps)
//   wv3: T_B''= M^T prod_{s=h2+1..h3} (diag(fe_s) M^T) (mB steps + fe=1 step)
//   wv1: bwd vector chain u_{h3+1} (len-2-h3 steps)
// The matrix step is the VERIFIED vector step applied to 4 independent
// column-tiles (D-col = lane&15 = B-col; the D->B tag relabel is per-column).
// Shared per-step pow2 rescale from tile0's representative; one ksum/wave.
// Combine (wv0, post-barrier): two 64x64 LDS matvecs + dot, f32, ~1us.
// Max segment ~len/4 ~ 128 steps vs R17's 256: 2x fewer serial steps.
#define BB 512
#define SS 512
#define TT 64
#define START_TAG 62
#define STOP_TAG 63

#define LOG2E 1.4426950408889634f
#define LN2   0.6931471805599453f

typedef _Float16 h2 __attribute__((ext_vector_type(2)));
typedef _Float16 h8 __attribute__((ext_vector_type(8)));
typedef float    f4 __attribute__((ext_vector_type(4)));

__device__ __forceinline__ h2 pkrtz(float a, float b) {
    return __builtin_bit_cast(h2, __builtin_amdgcn_cvt_pkrtz(a, b));
}
__device__ __forceinline__ f4 MF(h8 a, h8 b, f4 c) {
    return __builtin_amdgcn_mfma_f32_16x16x32_f16(a, b, c, 0, 0, 0);
}

__global__ void __launch_bounds__(256) crf_main(
    const float* __restrict__ feats, const int* __restrict__ mask,
    const int* __restrict__ tags, const float* __restrict__ trans,
    float* __restrict__ out)
{
    const int b    = blockIdx.x;
    const int tid  = threadIdx.x;
    const int wv   = tid >> 6;
    const int lane = tid & 63;
    const int g    = lane >> 4;
    const int cg   = lane & 15;

    const float* frow = feats + (size_t)b * SS * TT;
    const int*   mrow = mask + b * SS;

    __shared__ __align__(16) _Float16 febuf[4][8][TT];
    __shared__ __align__(16) _Float16 TAbuf[TT][TT];
    __shared__ __align__(16) _Float16 TBbuf[TT][TT];
    __shared__ __align__(16) float xbuf[TT], ubuf[TT], x2buf[TT];
    __shared__ int ks_sh[4];

    int cnt = 0;
    #pragma unroll
    for (int s = lane; s < SS; s += 64) cnt += (mrow[s] != 0);
    #pragma unroll
    for (int off = 32; off; off >>= 1) cnt += __shfl_xor(cnt, off);
    const int len = cnt;                 // in [SS/2, SS]

    int h1 = (len >> 2) - 9;             // fwd shortened: wv0 also does gold
    const int remt = len - 2 - h1;
    const int mA = remt / 3, mB = remt / 3;

    float offs = 0.f;
    int   ksum = 0;

    // ---- gold score on wv0 (before its chain; ~10 steps worth of work) ----
    if (wv == 0) {
        const int* trow = tags + b * SS;
        float acc = 0.f;
        for (int s = lane; s < SS; s += 64) {
            if (mrow[s] != 0) {
                const int tag  = trow[s];
                const int prev = (s == 0) ? START_TAG : trow[s - 1];
                acc += frow[(size_t)s * TT + tag] + trans[prev * TT + tag];
            }
        }
        #pragma unroll
        for (int off = 32; off; off >>= 1) acc += __shfl_xor(acc, off);
        if (lane == 0) {
            const int end_id = trow[len - 1];
            atomicAdd(out, -(acc + trans[end_id * TT + STOP_TAG]));
        }
    }

    // ---------------- per-wave chain parameters ----------------
    const bool isB   = (wv == 1);
    const bool isMat = (wv >= 2);
    const int nstep = (wv == 0) ? h1
                    : (wv == 1) ? (remt - mA - mB)
                    : (wv == 2) ? mA : mB;
    const int base  = (wv == 0) ? 1
                    : (wv == 1) ? (len - 2)
                    : (wv == 2) ? (h1 + 1) : (h1 + mA + 1);
    const int dir   = isB ? -1 : 1;
    _Float16 (*febw)[TT] = febuf[wv];

    const int to_base = 16 * (cg >> 2) + (cg & 3);
    // A fragments: fwd orientation exp(trans[kt][ot]) (M^T); bwd transposed.
    h8 A[4][2];
    #pragma unroll
    for (int tt = 0; tt < 4; ++tt)
        #pragma unroll
        for (int kc = 0; kc < 2; ++kc)
            #pragma unroll
            for (int j = 0; j < 8; ++j) {
                const int kt = 16 * g + 8 * kc + j;
                const int ot = to_base + 4 * tt;
                const int ix = isB ? (ot * TT + kt) : (kt * TT + ot);
                A[tt][kc][j] =
                    (_Float16)__builtin_amdgcn_exp2f(trans[ix] * LOG2E);
            }

    auto rowOf = [&](int idx) {
        int r = base + dir * idx;
        return r < 0 ? 0 : (r > SS - 1 ? SS - 1 : r);
    };

    // raw-feat ring + fe ring prologue (all chain waves)
    float fr[8];
    #pragma unroll
    for (int j = 0; j < 8; ++j)
        fr[j] = frow[(size_t)rowOf(j) * TT + lane];
    #pragma unroll
    for (int j = 0; j < 4; ++j)
        febw[rowOf(j) & 7][lane] =
            (_Float16)__builtin_amdgcn_exp2f(fr[j] * LOG2E);
    h8 cL0, cL1, cL2, cL3, cH0, cH1, cH2, cH3;
    {
        const _Float16* p0 = &febw[rowOf(0) & 7][16 * g];
        const _Float16* p1 = &febw[rowOf(1) & 7][16 * g];
        const _Float16* p2 = &febw[rowOf(2) & 7][16 * g];
        const _Float16* p3 = &febw[rowOf(3) & 7][16 * g];
        cL0 = *(const h8*)p0; cH0 = *(const h8*)(p0 + 8);
        cL1 = *(const h8*)p1; cH1 = *(const h8*)(p1 + 8);
        cL2 = *(const h8*)p2; cH2 = *(const h8*)(p2 + 8);
        cL3 = *(const h8*)p3; cH3 = *(const h8*)(p3 + 8);
    }
    const f4 Zz = {0.f, 0.f, 0.f, 0.f};

    if (!isMat) {
        // ================= vector chain (R17 verified) =================
        h8 B0, B1;
        if (wv == 0) {
            offs = frow[0] + trans[START_TAG * TT + 0];
            #pragma unroll
            for (int sl = 0; sl < 8; ++sl) {
                const int t0 = 16 * g + sl, t1 = t0 + 8;
                B0[sl] = (_Float16)__builtin_amdgcn_exp2f(
                    (frow[t0] + trans[START_TAG * TT + t0] - offs) * LOG2E);
                B1[sl] = (_Float16)__builtin_amdgcn_exp2f(
                    (frow[t1] + trans[START_TAG * TT + t1] - offs) * LOG2E);
            }
        } else {
            const float* fl = frow + (size_t)(len - 1) * TT;
            #pragma unroll
            for (int sl = 0; sl < 8; ++sl) {
                const int t0 = 16 * g + sl, t1 = t0 + 8;
                B0[sl] = (_Float16)__builtin_amdgcn_exp2f(
                    (fl[t0] + trans[t0 * TT + STOP_TAG]) * LOG2E);
                B1[sl] = (_Float16)__builtin_amdgcn_exp2f(
                    (fl[t1] + trans[t1 * TT + STOP_TAG]) * LOG2E);
            }
        }

        auto STEP = [&](h8 feL, h8 feH) {
            f4 d0 = MF(A[0][0], B0, Zz);
            f4 d1 = MF(A[1][0], B0, Zz);
            f4 d2 = MF(A[2][0], B0, Zz);
            f4 d3 = MF(A[3][0], B0, Zz);
            d0 = MF(A[0][1], B1, d0);
            d1 = MF(A[1][1], B1, d1);
            d2 = MF(A[2][1], B1, d2);
            d3 = MF(A[3][1], B1, d3);
            const int eb = (__builtin_amdgcn_readfirstlane(
                                __float_as_int(d0[0])) >> 23) & 0xff;
            ksum += eb - 127;
            const float sc = __int_as_float((254 - eb) << 23);
            const h2 p0 = pkrtz(d0[0] * sc, d0[1] * sc);
            const h2 p1 = pkrtz(d0[2] * sc, d0[3] * sc);
            const h2 p2 = pkrtz(d1[0] * sc, d1[1] * sc);
            const h2 p3 = pkrtz(d1[2] * sc, d1[3] * sc);
            const h2 p4 = pkrtz(d2[0] * sc, d2[1] * sc);
            const h2 p5 = pkrtz(d2[2] * sc, d2[3] * sc);
            const h2 p6 = pkrtz(d3[0] * sc, d3[1] * sc);
            const h2 p7 = pkrtz(d3[2] * sc, d3[3] * sc);
            const h2 q0 = p0 * __builtin_shufflevector(feL, feL, 0, 1);
            const h2 q1 = p1 * __builtin_shufflevector(feL, feL, 2, 3);
            const h2 q2 = p2 * __builtin_shufflevector(feL, feL, 4, 5);
            const h2 q3 = p3 * __builtin_shufflevector(feL, feL, 6, 7);
            const h2 q4 = p4 * __builtin_shufflevector(feH, feH, 0, 1);
            const h2 q5 = p5 * __builtin_shufflevector(feH, feH, 2, 3);
            const h2 q6 = p6 * __builtin_shufflevector(feH, feH, 4, 5);
            const h2 q7 = p7 * __builtin_shufflevector(feH, feH, 6, 7);
            B0 = __builtin_shufflevector(
                     __builtin_shufflevector(q0, q1, 0, 1, 2, 3),
                     __builtin_shufflevector(q2, q3, 0, 1, 2, 3),
                     0, 1, 2, 3, 4, 5, 6, 7);
            B1 = __builtin_shufflevector(
                     __builtin_shufflevector(q4, q5, 0, 1, 2, 3),
                     __builtin_shufflevector(q6, q7, 0, 1, 2, 3),
                     0, 1, 2, 3, 4, 5, 6, 7);
        };

        int i = 0;
        for (; i + 3 < nstep; i += 4) {
            const float n0 = frow[(size_t)rowOf(i + 8)  * TT + lane];
            const float n1 = frow[(size_t)rowOf(i + 9)  * TT + lane];
            const float n2 = frow[(size_t)rowOf(i + 10) * TT + lane];
            const float n3 = frow[(size_t)rowOf(i + 11) * TT + lane];
            febw[rowOf(i + 4) & 7][lane] =
                (_Float16)__builtin_amdgcn_exp2f(fr[4] * LOG2E);
            febw[rowOf(i + 5) & 7][lane] =
                (_Float16)__builtin_amdgcn_exp2f(fr[5] * LOG2E);
            febw[rowOf(i + 6) & 7][lane] =
                (_Float16)__builtin_amdgcn_exp2f(fr[6] * LOG2E);
            febw[rowOf(i + 7) & 7][lane] =
                (_Float16)__builtin_amdgcn_exp2f(fr[7] * LOG2E);
            const _Float16* q0p = &febw[rowOf(i + 4) & 7][16 * g];
            const _Float16* q1p = &febw[rowOf(i + 5) & 7][16 * g];
            const _Float16* q2p = &febw[rowOf(i + 6) & 7][16 * g];
            const _Float16* q3p = &febw[rowOf(i + 7) & 7][16 * g];
            const h8 nL0 = *(const h8*)q0p, nH0 = *(const h8*)(q0p + 8);
            const h8 nL1 = *(const h8*)q1p, nH1 = *(const h8*)(q1p + 8);
            const h8 nL2 = *(const h8*)q2p, nH2 = *(const h8*)(q2p + 8);
            const h8 nL3 = *(const h8*)q3p, nH3 = *(const h8*)(q3p + 8);

            STEP(cL0, cH0); STEP(cL1, cH1); STEP(cL2, cH2); STEP(cL3, cH3);

            cL0 = nL0; cH0 = nH0; cL1 = nL1; cH1 = nH1;
            cL2 = nL2; cH2 = nH2; cL3 = nL3; cH3 = nH3;
            #pragma unroll
            for (int j = 0; j < 4; ++j) fr[j] = fr[j + 4];
            fr[4] = n0; fr[5] = n1; fr[6] = n2; fr[7] = n3;
        }
        const int rem = nstep - i;
        if (rem > 0) STEP(cL0, cH0);
        if (rem > 1) STEP(cL1, cH1);
        if (rem > 2) STEP(cL2, cH2);

        float* obuf = (wv == 0) ? xbuf : ubuf;
        if (cg == 0) {
            #pragma unroll
            for (int sl = 0; sl < 8; ++sl) {
                obuf[16 * g + sl]     = (float)B0[sl];
                obuf[16 * g + 8 + sl] = (float)B1[sl];
            }
        }
        if (lane == 0) ks_sh[wv] = ksum;
    } else {
        // ================= matrix chain (4 column-tiles) =================
        h8 Bt0[4], Bt1[4];
        #pragma unroll
        for (int ct = 0; ct < 4; ++ct)
            #pragma unroll
            for (int sl = 0; sl < 8; ++sl) {
                Bt0[ct][sl] = (_Float16)((g == ct && cg == sl) ? 1.0f : 0.0f);
                Bt1[ct][sl] = (_Float16)((g == ct && cg == sl + 8) ? 1.0f : 0.0f);
            }

        auto MSTEP = [&](h8 feL, h8 feH, bool useFe) {
            f4 D[4][4];
            #pragma unroll
            for (int ct = 0; ct < 4; ++ct) {
                D[ct][0] = MF(A[0][0], Bt0[ct], Zz);
                D[ct][1] = MF(A[1][0], Bt0[ct], Zz);
                D[ct][2] = MF(A[2][0], Bt0[ct], Zz);
                D[ct][3] = MF(A[3][0], Bt0[ct], Zz);
            }
            #pragma unroll
            for (int ct = 0; ct < 4; ++ct) {
                D[ct][0] = MF(A[0][1], Bt1[ct], D[ct][0]);
                D[ct][1] = MF(A[1][1], Bt1[ct], D[ct][1]);
                D[ct][2] = MF(A[2][1], Bt1[ct], D[ct][2]);
                D[ct][3] = MF(A[3][1], Bt1[ct], D[ct][3]);
            }
            const int eb = (__builtin_amdgcn_readfirstlane(
                                __float_as_int(D[0][0][0])) >> 23) & 0xff;
            ksum += eb - 127;
            const float sc = __int_as_float((254 - eb) << 23);
            #pragma unroll
            for (int ct = 0; ct < 4; ++ct) {
                h2 p0 = pkrtz(D[ct][0][0] * sc, D[ct][0][1] * sc);
                h2 p1 = pkrtz(D[ct][0][2] * sc, D[ct][0][3] * sc);
                h2 p2 = pkrtz(D[ct][1][0] * sc, D[ct][1][1] * sc);
                h2 p3 = pkrtz(D[ct][1][2] * sc, D[ct][1][3] * sc);
                h2 p4 = pkrtz(D[ct][2][0] * sc, D[ct][2][1] * sc);
                h2 p5 = pkrtz(D[ct][2][2] * sc, D[ct][2][3] * sc);
                h2 p6 = pkrtz(D[ct][3][0] * sc, D[ct][3][1] * sc);
                h2 p7 = pkrtz(D[ct][3][2] * sc, D[ct][3][3] * sc);
                if (useFe) {
                    p0 = p0 * __builtin_shufflevector(feL, feL, 0, 1);
                    p1 = p1 * __builtin_shufflevector(feL, feL, 2, 3);
                    p2 = p2 * __builtin_shufflevector(feL, feL, 4, 5);
                    p3 = p3 * __builtin_shufflevector(feL, feL, 6, 7);
                    p4 = p4 * __builtin_shufflevector(feH, feH, 0, 1);
                    p5 = p5 * __builtin_shufflevector(feH, feH, 2, 3);
                    p6 = p6 * __builtin_shufflevector(feH, feH, 4, 5);
                    p7 = p7 * __builtin_shufflevector(feH, feH, 6, 7);
                }
                Bt0[ct] = __builtin_shufflevector(
                              __builtin_shufflevector(p0, p1, 0, 1, 2, 3),
                              __builtin_shufflevector(p2, p3, 0, 1, 2, 3),
                              0, 1, 2, 3, 4, 5, 6, 7);
                Bt1[ct] = __builtin_shufflevector(
                              __builtin_shufflevector(p4, p5, 0, 1, 2, 3),
                              __builtin_shufflevector(p6, p7, 0, 1, 2, 3),
                              0, 1, 2, 3, 4, 5, 6, 7);
            }
        };

        int i = 0;
        for (; i + 3 < nstep; i += 4) {
            const float n0 = frow[(size_t)rowOf(i + 8)  * TT + lane];
            const float n1 = frow[(size_t)rowOf(i + 9)  * TT + lane];
            const float n2 = frow[(size_t)rowOf(i + 10) * TT + lane];
            const float n3 = frow[(size_t)rowOf(i + 11) * TT + lane];
            febw[rowOf(i + 4) & 7][lane] =
                (_Float16)__builtin_amdgcn_exp2f(fr[4] * LOG2E);
            febw[rowOf(i + 5) & 7][lane] =
                (_Float16)__builtin_amdgcn_exp2f(fr[5] * LOG2E);
            febw[rowOf(i + 6) & 7][lane] =
                (_Float16)__builtin_amdgcn_exp2f(fr[6] * LOG2E);
            febw[rowOf(i + 7) & 7][lane] =
                (_Float16)__builtin_amdgcn_exp2f(fr[7] * LOG2E);
            const _Float16* q0p = &febw[rowOf(i + 4) & 7][16 * g];
            const _Float16* q1p = &febw[rowOf(i + 5) & 7][16 * g];
            const _Float16* q2p = &febw[rowOf(i + 6) & 7][16 * g];
            const _Float16* q3p = &febw[rowOf(i + 7) & 7][16 * g];
            const h8 nL0 = *(const h8*)q0p, nH0 = *(const h8*)(q0p + 8);
            const h8 nL1 = *(const h8*)q1p, nH1 = *(const h8*)(q1p + 8);
            const h8 nL2 = *(const h8*)q2p, nH2 = *(const h8*)(q2p + 8);
            const h8 nL3 = *(const h8*)q3p, nH3 = *(const h8*)(q3p + 8);

            MSTEP(cL0, cH0, true); MSTEP(cL1, cH1, true);
            MSTEP(cL2, cH2, true); MSTEP(cL3, cH3, true);

            cL0 = nL0; cH0 = nH0; cL1 = nL1; cH1 = nH1;
            cL2 = nL2; cH2 = nH2; cL3 = nL3; cH3 = nH3;
            #pragma unroll
            for (int j = 0; j < 4; ++j) fr[j] = fr[j + 4];
            fr[4] = n0; fr[5] = n1; fr[6] = n2; fr[7] = n3;
        }
        const int rem = nstep - i;
        if (rem > 0) MSTEP(cL0, cH0, true);
        if (rem > 1) MSTEP(cL1, cH1, true);
        if (rem > 2) MSTEP(cL2, cH2, true);

        // matB: one extra fe=1 step -> T_B'' = M^T T_B
        if (wv == 3) MSTEP(cL0, cH0, false);

        // publish T (rotated columns to avoid 32-way write conflicts):
        // T[i][j] stored at Tb[j][(i+2j)&63]
        _Float16* Tb = (wv == 2) ? &TAbuf[0][0] : &TBbuf[0][0];
        #pragma unroll
        for (int ct = 0; ct < 4; ++ct) {
            const int j = 16 * ct + cg;
            #pragma unroll
            for (int sl = 0; sl < 8; ++sl) {
                const int i0 = 16 * g + sl, i1 = i0 + 8;
                Tb[j * TT + ((i0 + 2 * j) & 63)] = Bt0[ct][sl];
                Tb[j * TT + ((i1 + 2 * j) & 63)] = Bt1[ct][sl];
            }
        }
        if (lane == 0) ks_sh[wv] = ksum;
    }

    __syncthreads();

    if (wv == 0) {
        // x2 = T_A x   (x = E_{h1} in xbuf)
        float a0 = 0.f, a1 = 0.f, a2 = 0.f, a3 = 0.f;
        #pragma unroll
        for (int j4 = 0; j4 < 16; ++j4) {
            const int j = 4 * j4;
            a0 += (float)TAbuf[j + 0][(lane + 2 * (j + 0)) & 63] * xbuf[j + 0];
            a1 += (float)TAbuf[j + 1][(lane + 2 * (j + 1)) & 63] * xbuf[j + 1];
            a2 += (float)TAbuf[j + 2][(lane + 2 * (j + 2)) & 63] * xbuf[j + 2];
            a3 += (float)TAbuf[j + 3][(lane + 2 * (j + 3)) & 63] * xbuf[j + 3];
        }
        x2buf[lane] = (a0 + a1) + (a2 + a3);
        // x3 = T_B'' x2
        float c0 = 0.f, c1 = 0.f, c2 = 0.f, c3 = 0.f;
        #pragma unroll
        for (int j4 = 0; j4 < 16; ++j4) {
            const int j = 4 * j4;
            c0 += (float)TBbuf[j + 0][(lane + 2 * (j + 0)) & 63] * x2buf[j + 0];
            c1 += (float)TBbuf[j + 1][(lane + 2 * (j + 1)) & 63] * x2buf[j + 1];
            c2 += (float)TBbuf[j + 2][(lane + 2 * (j + 2)) & 63] * x2buf[j + 2];
            c3 += (float)TBbuf[j + 3][(lane + 2 * (j + 3)) & 63] * x2buf[j + 3];
        }
        const float x3 = (c0 + c1) + (c2 + c3);
        // Z = u . x3
        float z = ubuf[lane] * x3;
        #pragma unroll
        for (int off = 32; off; off >>= 1) z += __shfl_xor(z, off);
        if (lane == 0)
            atomicAdd(out, offs
                      + (float)(ksum + ks_sh[1] + ks_sh[2] + ks_sh[3]) * LN2
                      + LN2 * __builtin_amdgcn_logf(z));
    }
}

extern "C" void kernel_launch(void* const* d_in, const int* in_sizes, int n_in,
                              void* d_out, int out_size, void* d_ws, size_t ws_size,
                              hipStream_t stream) {
    const float* feats = (const float*)d_in[0];   // (B,S,T) f32
    const int*   mask  = (const int*)d_in[1];     // (B,S)   int (0/1)
    const int*   tags  = (const int*)d_in[2];     // (B,S)   int
    const float* trans = (const float*)d_in[3];   // (T,T)   f32
    float* out = (float*)d_out;

    (void)hipMemsetAsync(out, 0, sizeof(float), stream);
    crf_main<<<BB, 256, 0, stream>>>(feats, mask, tags, trans, out);
}

// Round 10
// 165.876 us; speedup vs baseline: 1.2961x; 1.2961x over previous
//
#include <hip/hip_runtime.h>

// CRF NLL, round 19: R17's bidirectional split (verified absmax 0.0, 89us)
// with the step body restored to R12c's EXACT form (measured 520 cy/step):
// fe read in-step from LDS via 2 uniform-address ds_read_b128 (latency hides
// under the MFMA drain), NO register staging of fe.
//
// Why: R17's in-loop fe reg preload (8 live h8 = +32 VGPR) inflated the step
// 520->830 cy; R18's wider matrix state (160+ VGPR) serialized tiles at
// ~2900 cy/step. Narrow per-wave state is what keeps the chain at 520.
//
// fwd:  E_s = fe_s (*) (M^T E_{s-1}),  s=1..h;  then V = M^T E_h (bare)
// bwd:  u_{len-1} = exp(f_{len-1}+trans[:,STOP]);
//       u_s = fe_s (*) (M u_{s+1}),    s=len-2..h+1
// Z = sum_t V[t]*u_{h+1}[t];  logZ = offs + (ksf+ksb)*ln2 + ln(Z)
#define BB 512
#define SS 512
#define TT 64
#define START_TAG 62
#define STOP_TAG 63

#define LOG2E 1.4426950408889634f
#define LN2   0.6931471805599453f

typedef _Float16 h2 __attribute__((ext_vector_type(2)));
typedef _Float16 h8 __attribute__((ext_vector_type(8)));
typedef float    f4 __attribute__((ext_vector_type(4)));

__device__ __forceinline__ h2 pkrtz(float a, float b) {
    return __builtin_bit_cast(h2, __builtin_amdgcn_cvt_pkrtz(a, b));
}
__device__ __forceinline__ f4 MF(h8 a, h8 b, f4 c) {
    return __builtin_amdgcn_mfma_f32_16x16x32_f16(a, b, c, 0, 0, 0);
}

__global__ void __launch_bounds__(192) crf_main(
    const float* __restrict__ feats, const int* __restrict__ mask,
    const int* __restrict__ tags, const float* __restrict__ trans,
    float* __restrict__ out)
{
    const int b    = blockIdx.x;
    const int tid  = threadIdx.x;
    const int wv   = tid >> 6;
    const int lane = tid & 63;

    const float* frow = feats + (size_t)b * SS * TT;
    const int*   mrow = mask + b * SS;

    __shared__ __align__(16) _Float16 febuf[2][8][TT];
    __shared__ __align__(16) float xbuf[TT];   // V = M^T E_h (f32)
    __shared__ __align__(16) float ybuf[TT];   // u_{h+1}     (f32)
    __shared__ int ks_sh;                      // bwd ksum

    int cnt = 0;
    #pragma unroll
    for (int s = lane; s < SS; s += 64) cnt += (mrow[s] != 0);
    #pragma unroll
    for (int off = 32; off; off >>= 1) cnt += __shfl_xor(cnt, off);
    const int len = cnt;            // in [SS/2, SS]
    const int h   = len >> 1;

    float offs = 0.f;
    int   ksum = 0;

    if (wv < 2) {
        // ------------- chain wave: wv0 = forward, wv1 = backward -------------
        const bool isF = (wv == 0);
        const int g  = lane >> 4;
        const int cg = lane & 15;
        const int to_base = 16 * (cg >> 2) + (cg & 3);
        const int nstep = isF ? h : (len - h - 2);
        const int base  = isF ? 1 : (len - 2);   // fe row of step i = base+dir*i
        const int dir   = isF ? 1 : -1;
        _Float16 (*febw)[TT] = febuf[wv];

        // A fragments: fwd = exp(trans[kt][ot]) (M^T), bwd = exp(trans[ot][kt]) (M)
        h8 A[4][2];
        #pragma unroll
        for (int tt = 0; tt < 4; ++tt)
            #pragma unroll
            for (int kc = 0; kc < 2; ++kc)
                #pragma unroll
                for (int j = 0; j < 8; ++j) {
                    const int kt = 16 * g + 8 * kc + j;
                    const int ot = to_base + 4 * tt;
                    const int ix = isF ? (kt * TT + ot) : (ot * TT + kt);
                    A[tt][kc][j] =
                        (_Float16)__builtin_amdgcn_exp2f(trans[ix] * LOG2E);
                }

        // B init (slots = raw tags 16g+sl)
        h8 B0, B1;
        if (isF) {
            offs = frow[0] + trans[START_TAG * TT + 0];   // wave-uniform
            #pragma unroll
            for (int sl = 0; sl < 8; ++sl) {
                const int t0 = 16 * g + sl, t1 = t0 + 8;
                B0[sl] = (_Float16)__builtin_amdgcn_exp2f(
                    (frow[t0] + trans[START_TAG * TT + t0] - offs) * LOG2E);
                B1[sl] = (_Float16)__builtin_amdgcn_exp2f(
                    (frow[t1] + trans[START_TAG * TT + t1] - offs) * LOG2E);
            }
        } else {
            const float* fl = frow + (size_t)(len - 1) * TT;
            #pragma unroll
            for (int sl = 0; sl < 8; ++sl) {
                const int t0 = 16 * g + sl, t1 = t0 + 8;
                B0[sl] = (_Float16)__builtin_amdgcn_exp2f(
                    (fl[t0] + trans[t0 * TT + STOP_TAG]) * LOG2E);
                B1[sl] = (_Float16)__builtin_amdgcn_exp2f(
                    (fl[t1] + trans[t1 * TT + STOP_TAG]) * LOG2E);
            }
        }

        auto rowOf = [&](int idx) {
            int r = base + dir * idx;
            return r < 0 ? 0 : (r > SS - 1 ? SS - 1 : r);
        };

        // raw-feat ring (rows for steps i..i+7)
        float fr[8];
        #pragma unroll
        for (int j = 0; j < 8; ++j)
            fr[j] = frow[(size_t)rowOf(j) * TT + lane];
        // prologue: fe rows for steps 0..3
        #pragma unroll
        for (int j = 0; j < 4; ++j)
            febw[rowOf(j) & 7][lane] =
                (_Float16)__builtin_amdgcn_exp2f(fr[j] * LOG2E);

        const f4 Zz = {0.f, 0.f, 0.f, 0.f};
        // R12c step body: fe read in-step from LDS (uniform b128 broadcast);
        // read issues at step top, first use after pkrtz -> latency hidden.
        auto STEP = [&](int row) {
            const _Float16* fb = &febw[row & 7][16 * g];
            const h8 feL = *(const h8*)(fb);
            const h8 feH = *(const h8*)(fb + 8);
            f4 d0 = MF(A[0][0], B0, Zz);
            f4 d1 = MF(A[1][0], B0, Zz);
            f4 d2 = MF(A[2][0], B0, Zz);
            f4 d3 = MF(A[3][0], B0, Zz);
            d0 = MF(A[0][1], B1, d0);
            d1 = MF(A[1][1], B1, d1);
            d2 = MF(A[2][1], B1, d2);
            d3 = MF(A[3][1], B1, d3);
            const int eb = (__builtin_amdgcn_readfirstlane(
                                __float_as_int(d0[0])) >> 23) & 0xff;
            ksum += eb - 127;
            const float sc = __int_as_float((254 - eb) << 23);
            const h2 p0 = pkrtz(d0[0] * sc, d0[1] * sc);
            const h2 p1 = pkrtz(d0[2] * sc, d0[3] * sc);
            const h2 p2 = pkrtz(d1[0] * sc, d1[1] * sc);
            const h2 p3 = pkrtz(d1[2] * sc, d1[3] * sc);
            const h2 p4 = pkrtz(d2[0] * sc, d2[1] * sc);
            const h2 p5 = pkrtz(d2[2] * sc, d2[3] * sc);
            const h2 p6 = pkrtz(d3[0] * sc, d3[1] * sc);
            const h2 p7 = pkrtz(d3[2] * sc, d3[3] * sc);
            const h2 q0 = p0 * __builtin_shufflevector(feL, feL, 0, 1);
            const h2 q1 = p1 * __builtin_shufflevector(feL, feL, 2, 3);
            const h2 q2 = p2 * __builtin_shufflevector(feL, feL, 4, 5);
            const h2 q3 = p3 * __builtin_shufflevector(feL, feL, 6, 7);
            const h2 q4 = p4 * __builtin_shufflevector(feH, feH, 0, 1);
            const h2 q5 = p5 * __builtin_shufflevector(feH, feH, 2, 3);
            const h2 q6 = p6 * __builtin_shufflevector(feH, feH, 4, 5);
            const h2 q7 = p7 * __builtin_shufflevector(feH, feH, 6, 7);
            B0 = __builtin_shufflevector(
                     __builtin_shufflevector(q0, q1, 0, 1, 2, 3),
                     __builtin_shufflevector(q2, q3, 0, 1, 2, 3),
                     0, 1, 2, 3, 4, 5, 6, 7);
            B1 = __builtin_shufflevector(
                     __builtin_shufflevector(q4, q5, 0, 1, 2, 3),
                     __builtin_shufflevector(q6, q7, 0, 1, 2, 3),
                     0, 1, 2, 3, 4, 5, 6, 7);
        };

        int i = 0;
        for (; i + 3 < nstep; i += 4) {
            const float n0 = frow[(size_t)rowOf(i + 8)  * TT + lane];
            const float n1 = frow[(size_t)rowOf(i + 9)  * TT + lane];
            const float n2 = frow[(size_t)rowOf(i + 10) * TT + lane];
            const float n3 = frow[(size_t)rowOf(i + 11) * TT + lane];
            febw[rowOf(i + 4) & 7][lane] =
                (_Float16)__builtin_amdgcn_exp2f(fr[4] * LOG2E);
            febw[rowOf(i + 5) & 7][lane] =
                (_Float16)__builtin_amdgcn_exp2f(fr[5] * LOG2E);
            febw[rowOf(i + 6) & 7][lane] =
                (_Float16)__builtin_amdgcn_exp2f(fr[6] * LOG2E);
            febw[rowOf(i + 7) & 7][lane] =
                (_Float16)__builtin_amdgcn_exp2f(fr[7] * LOG2E);

            STEP(rowOf(i)); STEP(rowOf(i + 1));
            STEP(rowOf(i + 2)); STEP(rowOf(i + 3));

            #pragma unroll
            for (int j = 0; j < 4; ++j) fr[j] = fr[j + 4];
            fr[4] = n0; fr[5] = n1; fr[6] = n2; fr[7] = n3;
        }

        const int rem = nstep - i;   // 0..3
        if (rem > 0) STEP(rowOf(i));
        if (rem > 1) STEP(rowOf(i + 1));
        if (rem > 2) STEP(rowOf(i + 2));

        if (isF) {
            // V = M^T E_h (bare matvec, rescaled), publish f32
            f4 d0 = MF(A[0][0], B0, Zz);
            f4 d1 = MF(A[1][0], B0, Zz);
            f4 d2 = MF(A[2][0], B0, Zz);
            f4 d3 = MF(A[3][0], B0, Zz);
            d0 = MF(A[0][1], B1, d0);
            d1 = MF(A[1][1], B1, d1);
            d2 = MF(A[2][1], B1, d2);
            d3 = MF(A[3][1], B1, d3);
            const int eb = (__builtin_amdgcn_readfirstlane(
                                __float_as_int(d0[0])) >> 23) & 0xff;
            ksum += eb - 127;
            const float sc = __int_as_float((254 - eb) << 23);
            if (cg == 0) {
                #pragma unroll
                for (int r = 0; r < 4; ++r) {
                    xbuf[16 * g + 0 * 4 + r] = d0[r] * sc;
                    xbuf[16 * g + 1 * 4 + r] = d1[r] * sc;
                    xbuf[16 * g + 2 * 4 + r] = d2[r] * sc;
                    xbuf[16 * g + 3 * 4 + r] = d3[r] * sc;
                }
            }
        } else {
            if (cg == 0) {
                #pragma unroll
                for (int sl = 0; sl < 8; ++sl) {
                    ybuf[16 * g + sl]     = (float)B0[sl];
                    ybuf[16 * g + 8 + sl] = (float)B1[sl];
                }
            }
            if (lane == 0) ks_sh = ksum;
        }
    } else {
        // ---------------- gold score, wave 2 --------------------------------
        const int* trow = tags + b * SS;
        float acc = 0.f;
        for (int s = lane; s < SS; s += 64) {
            if (mrow[s] != 0) {
                const int tag  = trow[s];
                const int prev = (s == 0) ? START_TAG : trow[s - 1];
                acc += frow[(size_t)s * TT + tag] + trans[prev * TT + tag];
            }
        }
        #pragma unroll
        for (int off = 32; off; off >>= 1) acc += __shfl_xor(acc, off);
        if (lane == 0) {
            const int end_id = trow[len - 1];
            atomicAdd(out, -(acc + trans[end_id * TT + STOP_TAG]));
        }
    }

    __syncthreads();

    if (wv == 0) {
        // Z = sum_t V[t] * u_{h+1}[t]
        float z = xbuf[lane] * ybuf[lane];
        #pragma unroll
        for (int off = 32; off; off >>= 1) z += __shfl_xor(z, off);
        if (lane == 0)
            atomicAdd(out, offs + (float)(ksum + ks_sh) * LN2
                           + LN2 * __builtin_amdgcn_logf(z));
    }
}

extern "C" void kernel_launch(void* const* d_in, const int* in_sizes, int n_in,
                              void* d_out, int out_size, void* d_ws, size_t ws_size,
                              hipStream_t stream) {
    const float* feats = (const float*)d_in[0];   // (B,S,T) f32
    const int*   mask  = (const int*)d_in[1];     // (B,S)   int (0/1)
    const int*   tags  = (const int*)d_in[2];     // (B,S)   int
    const float* trans = (const float*)d_in[3];   // (T,T)   f32
    float* out = (float*)d_out;

    (void)hipMemsetAsync(out, 0, sizeof(float), stream);
    crf_main<<<BB, 192, 0, stream>>>(feats, mask, tags, trans, out);
}